// Round 1
// baseline (695.045 us; speedup 1.0000x reference)
//
#include <hip/hip_runtime.h>

#define NB 64
#define NC 64
#define NH 112
#define NW 112
#define NHW (NH*NW)          // 12544
#define NTILES (NHW/64)      // 196
#define S_CHUNKS 8
#define BN_EPS 1e-5f

typedef __attribute__((ext_vector_type(8))) short bf16x8;          // 8 bf16 (4 VGPR) MFMA A/B frag
typedef __attribute__((ext_vector_type(4))) float f32x4;           // MFMA C/D frag
typedef __attribute__((ext_vector_type(4))) unsigned short us4;    // 8B LDS store

#define MFMA16(a,b,c) __builtin_amdgcn_mfma_f32_16x16x32_bf16(a,b,c,0,0,0)

__device__ __forceinline__ float bf2f(unsigned short u) {
    return __uint_as_float(((unsigned int)u) << 16);
}
__device__ __forceinline__ float bfl(unsigned int u) { return __uint_as_float(u << 16); }
__device__ __forceinline__ float bfh(unsigned int u) { return __uint_as_float(u & 0xffff0000u); }
__device__ __forceinline__ unsigned short f2bf(float f) {
    unsigned int u = __float_as_uint(f);
    return (unsigned short)((u + 0x7fffu + ((u >> 16) & 1u)) >> 16);
}

// dtype-agnostic scalar load: F32 -> float, else bf16 bits
template<bool F32>
__device__ __forceinline__ float ld1(const void* p, size_t i) {
    if constexpr (F32) return ((const float*)p)[i];
    else               return bf2f(((const unsigned short*)p)[i]);
}

// 8 consecutive elements -> bf16x8 fragment (fp32: convert; bf16: direct 16B load)
template<bool F32>
__device__ __forceinline__ bf16x8 ldfrag8(const void* p, int idx) {
    bf16x8 r;
    if constexpr (F32) {
        const float* f = (const float*)p + idx;
        float4 a = *(const float4*)f;
        float4 b = *(const float4*)(f + 4);
        r[0] = (short)f2bf(a.x); r[1] = (short)f2bf(a.y);
        r[2] = (short)f2bf(a.z); r[3] = (short)f2bf(a.w);
        r[4] = (short)f2bf(b.x); r[5] = (short)f2bf(b.y);
        r[6] = (short)f2bf(b.z); r[7] = (short)f2bf(b.w);
    } else {
        r = *(const bf16x8*)((const unsigned short*)p + idx);
    }
    return r;
}

// Detect fp32 data read as ushorts: lo-half mantissa words hit exp==0xFF
// (NaN pattern) with p~1/256; bf16 N(0,1) data never has exp==0xFF.
__device__ __forceinline__ bool detect_f32(const unsigned short* x) {
    int cnt = 0;
    for (int i = threadIdx.x; i < 8192; i += 256) {
        unsigned short u = x[i];
        cnt += ((u & 0x7F80u) == 0x7F80u) ? 1 : 0;
    }
    #pragma unroll
    for (int d = 1; d < 64; d <<= 1) cnt += __shfl_xor(cnt, d, 64);
    __shared__ int dsh[4];
    int wid = threadIdx.x >> 6;
    if ((threadIdx.x & 63) == 0) dsh[wid] = cnt;
    __syncthreads();
    int total = dsh[0] + dsh[1] + dsh[2] + dsh[3];
    __syncthreads();
    return total >= 2;
}

// ---------------------------------------------------------------------------
// Kernel 1 (MFMA rewrite): fused value/key 1x1 convs + BN + channel softmax +
// context matmul. Grid: NB*S_CHUNKS=512 blocks (2/CU), 256 threads (4 waves).
//
// Per 64-position tile:
//   XT[p][c] bf16 in LDS (XOR-swizzled) = transposed X tile
//   conv: OUT[o][p] = W[o][c] x XT  -> A = W (in VGPR frags), B = XT rows
//         wave `wid` owns p-strip [64o][16p]: B-frag shared by 4 o-tiles x 2 convs
//   softmax over o: each lane holds 16 o-values at its column p -> 15 VALU max
//         + 2 shfl (strides 16,32), exp, sum likewise. (replaces 192 ds_swizzle)
//   KT/VT[o][p] bf16 in LDS (same swizzle)
//   ctx[i][j] += sum_p K[i][p]*V[j][p]: A = KT rows, B = VT rows, acc in VGPRs.
//
// A/B frags are loaded as contiguous-8 along k: the HW k-slot permutation is
// identical for A and B so it cancels; only the C/D layout (col=lane&15,
// row=(lane>>4)*4+reg, HW-verified) is relied on explicitly.
// LDS row stride = 128B -> 16-way bank conflict unswizzled; all reads/writes
// use byte_off ^= (row&7)<<4 (2-way residual, free).
// ---------------------------------------------------------------------------
template<bool F32>
__device__ void ctx_impl(const void* __restrict__ xv, const void* __restrict__ Wv,
                         const void* __restrict__ bv, const void* __restrict__ Wm,
                         const void* __restrict__ bm, const void* __restrict__ g_,
                         const void* __restrict__ be_, const void* __restrict__ me_,
                         const void* __restrict__ va_, float* __restrict__ ctx,
                         char* XTb, char* KTb, char* VTb)
{
    const int tid  = threadIdx.x;
    const int b    = blockIdx.x / S_CHUNKS;
    const int s    = blockIdx.x % S_CHUNKS;
    const int lane = tid & 63;
    const int wid  = tid >> 6;
    const int lh   = lane >> 4;   // 0..3
    const int ll   = lane & 15;   // 0..15

    // ---- per-lane BN/bias params for the 16 conv-D o-values: o = 16*(q>>2) + 4*lh + (q&3)
    float scale16[16], off16[16], bv16[16];
    #pragma unroll
    for (int q = 0; q < 16; ++q) {
        int o = 16 * (q >> 2) + 4 * lh + (q & 3);
        float sc = ld1<F32>(g_, o) * (1.0f / sqrtf(ld1<F32>(va_, o) + BN_EPS));
        scale16[q] = sc;
        off16[q]   = (ld1<F32>(bm, o) - ld1<F32>(me_, o)) * sc + ld1<F32>(be_, o);
        bv16[q]    = ld1<F32>(bv, o);
    }

    // ---- W fragments in registers (A-operand): row o = 16*ot + ll, k = 32*kk + 8*lh
    bf16x8 wvf[4][2], wmf[4][2];   // 64 VGPRs
    #pragma unroll
    for (int ot = 0; ot < 4; ++ot)
        #pragma unroll
        for (int kk = 0; kk < 2; ++kk) {
            int idx = (16 * ot + ll) * 64 + 32 * kk + 8 * lh;
            wvf[ot][kk] = ldfrag8<F32>(Wv, idx);
            wmf[ot][kk] = ldfrag8<F32>(Wm, idx);
        }

    // ---- ctx accumulators: wave owns i-tile = wid, j-tiles 0..3
    f32x4 cacc[4];
    #pragma unroll
    for (int tj = 0; tj < 4; ++tj)
        #pragma unroll
        for (int e = 0; e < 4; ++e) cacc[tj][e] = 0.0f;

    const int c0 = 16 * wid + 4 * lh;   // staging: 4 consecutive channels
    const int p0 = ll * 4;              // staging: 4 consecutive positions
    const int pB = 16 * wid + ll;       // this lane's output column p
    const size_t xbase = (size_t)b * (NC * NHW);

    for (int t = s; t < NTILES; t += S_CHUNKS) {
        // ---- A: stage XT[p][c] bf16, swizzled. Coalesced global reads (16 lanes
        // x consecutive p), transposed b64 LDS writes (4 bf16 along c).
        {
            unsigned short vs[4][4];   // [ci][pi]
            if constexpr (F32) {
                const float* xp = (const float*)xv + xbase + (size_t)t * 64 + p0;
                #pragma unroll
                for (int ci = 0; ci < 4; ++ci) {
                    float4 v = *(const float4*)(xp + (size_t)(c0 + ci) * NHW);
                    vs[ci][0] = f2bf(v.x); vs[ci][1] = f2bf(v.y);
                    vs[ci][2] = f2bf(v.z); vs[ci][3] = f2bf(v.w);
                }
            } else {
                const unsigned short* xp = (const unsigned short*)xv + xbase + (size_t)t * 64 + p0;
                #pragma unroll
                for (int ci = 0; ci < 4; ++ci) {
                    uint2 v = *(const uint2*)(xp + (size_t)(c0 + ci) * NHW);
                    vs[ci][0] = (unsigned short)(v.x & 0xffffu);
                    vs[ci][1] = (unsigned short)(v.x >> 16);
                    vs[ci][2] = (unsigned short)(v.y & 0xffffu);
                    vs[ci][3] = (unsigned short)(v.y >> 16);
                }
            }
            #pragma unroll
            for (int pi = 0; pi < 4; ++pi) {
                int p = p0 + pi;
                int off = ((p << 7) + (c0 << 1)) ^ ((p & 7) << 4);
                us4 w; w[0] = vs[0][pi]; w[1] = vs[1][pi]; w[2] = vs[2][pi]; w[3] = vs[3][pi];
                *(us4*)(XTb + off) = w;
            }
        }
        __syncthreads();   // XT visible; prev-iter KT/VT readers (mm2) done

        // ---- C: conv MFMAs. B-frag = XT row pB, shared by 4 o-tiles x 2 convs.
        f32x4 kacc[4], vacc[4];
        #pragma unroll
        for (int q = 0; q < 4; ++q)
            #pragma unroll
            for (int e = 0; e < 4; ++e) { kacc[q][e] = 0.0f; vacc[q][e] = 0.0f; }

        #pragma unroll
        for (int kk = 0; kk < 2; ++kk) {
            int off = ((pB << 7) + ((32 * kk + 8 * lh) << 1)) ^ ((pB & 7) << 4);
            bf16x8 xb = *(const bf16x8*)(XTb + off);
            #pragma unroll
            for (int ot = 0; ot < 4; ++ot) {
                vacc[ot] = MFMA16(wvf[ot][kk], xb, vacc[ot]);
                kacc[ot] = MFMA16(wmf[ot][kk], xb, kacc[ot]);
            }
        }

        // ---- softmax over o at column pB: 16 in-lane values + butterfly over lh
        float kb[16];
        float mx = -1e30f;
        #pragma unroll
        for (int q = 0; q < 16; ++q) {
            float v = fmaf(kacc[q >> 2][q & 3], scale16[q], off16[q]);
            kb[q] = v;
            mx = fmaxf(mx, v);
        }
        mx = fmaxf(mx, __shfl_xor(mx, 16, 64));
        mx = fmaxf(mx, __shfl_xor(mx, 32, 64));
        float ss = 0.0f;
        #pragma unroll
        for (int q = 0; q < 16; ++q) {
            float e = __expf(kb[q] - mx);
            kb[q] = e;
            ss += e;
        }
        ss += __shfl_xor(ss, 16, 64);
        ss += __shfl_xor(ss, 32, 64);
        float rs = 1.0f / ss;

        // ---- D: write KT/VT[o][p] bf16 (swizzled). lanes 0-15 write 32B runs -> conflict-free
        #pragma unroll
        for (int q = 0; q < 16; ++q) {
            int o = 16 * (q >> 2) + 4 * lh + (q & 3);
            int off = ((o << 7) + (pB << 1)) ^ ((o & 7) << 4);
            *(unsigned short*)(KTb + off) = f2bf(kb[q] * rs);
            *(unsigned short*)(VTb + off) = f2bf(vacc[q >> 2][q & 3] + bv16[q]);
        }
        __syncthreads();   // KT/VT complete; XT consumed

        // ---- E: ctx MFMAs: D[i][j] += sum_p K[i][p]*V[j][p] (k = p, 2 steps)
        #pragma unroll
        for (int kk = 0; kk < 2; ++kk) {
            int ra = 16 * wid + ll;
            int aoff = ((ra << 7) + ((32 * kk + 8 * lh) << 1)) ^ ((ra & 7) << 4);
            bf16x8 af = *(const bf16x8*)(KTb + aoff);
            #pragma unroll
            for (int tj = 0; tj < 4; ++tj) {
                int rb = 16 * tj + ll;
                int boff = ((rb << 7) + ((32 * kk + 8 * lh) << 1)) ^ ((rb & 7) << 4);
                bf16x8 bfr = *(const bf16x8*)(VTb + boff);
                cacc[tj] = MFMA16(af, bfr, cacc[tj]);
            }
        }
    }

    // ---- epilogue: ctx[i][j], i = 16*wid + 4*lh + r (C/D row map), j = 16*tj + ll
    float* cb = ctx + ((size_t)b << 12);
    #pragma unroll
    for (int tj = 0; tj < 4; ++tj)
        #pragma unroll
        for (int r = 0; r < 4; ++r)
            atomicAdd(&cb[(16 * wid + 4 * lh + r) * 64 + 16 * tj + ll], cacc[tj][r]);
}

__global__ __launch_bounds__(256) void ctx_kernel(
    const void* __restrict__ x, const void* __restrict__ Wv, const void* __restrict__ bv,
    const void* __restrict__ Wm, const void* __restrict__ bm, const void* __restrict__ g_,
    const void* __restrict__ be_, const void* __restrict__ me_, const void* __restrict__ va_,
    float* __restrict__ ctx)
{
    __shared__ __align__(16) char XTb[8192];   // XT[p][c] bf16, swizzled
    __shared__ __align__(16) char KTb[8192];   // Ksm[o][p] bf16, swizzled
    __shared__ __align__(16) char VTb[8192];   // V[o][p] bf16, swizzled
    if (detect_f32((const unsigned short*)x))
        ctx_impl<true >(x, Wv, bv, Wm, bm, g_, be_, me_, va_, ctx, XTb, KTb, VTb);
    else
        ctx_impl<false>(x, Wv, bv, Wm, bm, g_, be_, me_, va_, ctx, XTb, KTb, VTb);
}

// ---------------------------------------------------------------------------
// Kernel 2 (unchanged): per-(b,c) plane — recompute 9 dynamic weights from ctx
// (sigmoid + grouped fc) then depthwise 3x3 conv, pad 1. Grid: NB*NC=4096.
// ---------------------------------------------------------------------------
template<bool F32>
__device__ void dwconv_impl(const void* __restrict__ xv, const float* __restrict__ ctx,
                            const void* __restrict__ Wfc, const void* __restrict__ bfc,
                            void* __restrict__ outv, float* wsm, float* attS)
{
    const int bc = blockIdx.x;
    const int b = bc >> 6, i = bc & 63;
    const int tid = threadIdx.x, lane = tid & 63, wid = tid >> 6;

    if (wid == 0) {
        float cv = ctx[((size_t)b << 12) + (i << 6) + lane];
        attS[lane] = 1.0f / (1.0f + __expf(-cv));
    }
    __syncthreads();

    for (int j = wid; j < 9; j += 4) {
        float p = attS[lane] * ld1<F32>(Wfc, (size_t)(i * 9 + j) * 64 + lane);
        #pragma unroll
        for (int d = 1; d < 64; d <<= 1) p += __shfl_xor(p, d, 64);
        if (lane == 0) wsm[j] = p + ld1<F32>(bfc, i * 9 + j);
    }
    __syncthreads();

    const float w0 = wsm[0], w1 = wsm[1], w2 = wsm[2],
                w3 = wsm[3], w4 = wsm[4], w5 = wsm[5],
                w6 = wsm[6], w7 = wsm[7], w8 = wsm[8];
    const size_t base = (size_t)bc * NHW;

    for (int idx = tid; idx < NHW; idx += 256) {
        int y  = idx / NW;
        int xx = idx - y * NW;
        float sum;
        if (y >= 1 && y <= NH - 2 && xx >= 1 && xx <= NW - 2) {
            sum = w0 * ld1<F32>(xv, base + idx - NW - 1) + w1 * ld1<F32>(xv, base + idx - NW) + w2 * ld1<F32>(xv, base + idx - NW + 1)
                + w3 * ld1<F32>(xv, base + idx - 1)      + w4 * ld1<F32>(xv, base + idx)      + w5 * ld1<F32>(xv, base + idx + 1)
                + w6 * ld1<F32>(xv, base + idx + NW - 1) + w7 * ld1<F32>(xv, base + idx + NW) + w8 * ld1<F32>(xv, base + idx + NW + 1);
        } else {
            sum = 0.0f;
            const float wr[9] = { w0, w1, w2, w3, w4, w5, w6, w7, w8 };
            #pragma unroll
            for (int dy = -1; dy <= 1; ++dy)
                #pragma unroll
                for (int dx = -1; dx <= 1; ++dx) {
                    int yy = y + dy, xc = xx + dx;
                    if (yy >= 0 && yy < NH && xc >= 0 && xc < NW)
                        sum += wr[(dy + 1) * 3 + (dx + 1)] * ld1<F32>(xv, base + yy * NW + xc);
                }
        }
        if constexpr (F32) ((float*)outv)[base + idx] = sum;
        else               ((unsigned short*)outv)[base + idx] = f2bf(sum);
    }
}

__global__ __launch_bounds__(256) void dwconv_kernel(
    const void* __restrict__ x, const float* __restrict__ ctx,
    const void* __restrict__ Wfc, const void* __restrict__ bfc, void* __restrict__ out)
{
    __shared__ float wsm[12];
    __shared__ float attS[64];
    if (detect_f32((const unsigned short*)x))
        dwconv_impl<true >(x, ctx, Wfc, bfc, out, wsm, attS);
    else
        dwconv_impl<false>(x, ctx, Wfc, bfc, out, wsm, attS);
}

extern "C" void kernel_launch(void* const* d_in, const int* in_sizes, int n_in,
                              void* d_out, int out_size, void* d_ws, size_t ws_size,
                              hipStream_t stream) {
    const void* x     = d_in[0];
    const void* Wv    = d_in[1];
    const void* bv    = d_in[2];
    const void* Wm    = d_in[3];
    const void* bm    = d_in[4];
    const void* gamma = d_in[5];
    const void* beta  = d_in[6];
    const void* mean  = d_in[7];
    const void* var   = d_in[8];
    const void* Wfc   = d_in[9];
    const void* bfc   = d_in[10];

    float* ctx = (float*)d_ws;   // exactly 64*64*64*4 = 1,048,576 bytes — total ws use

    hipMemsetAsync(ctx, 0, (size_t)NB * NC * NC * sizeof(float), stream);
    ctx_kernel<<<NB * S_CHUNKS, 256, 0, stream>>>(x, Wv, bv, Wm, bm, gamma, beta, mean, var, ctx);
    dwconv_kernel<<<NB * NC, 256, 0, stream>>>(x, ctx, Wfc, bfc, d_out);
}

// Round 2
// 547.202 us; speedup vs baseline: 1.2702x; 1.2702x over previous
//
#include <hip/hip_runtime.h>

#define NB 64
#define NC 64
#define NH 112
#define NW 112
#define NHW (NH*NW)          // 12544
#define NTILES (NHW/64)      // 196
#define S_CHUNKS 8
#define BN_EPS 1e-5f

typedef __attribute__((ext_vector_type(8))) short bf16x8;          // 8 bf16 (4 VGPR) MFMA A/B frag
typedef __attribute__((ext_vector_type(4))) float f32x4;           // MFMA C/D frag
typedef __attribute__((ext_vector_type(4))) unsigned short us4;    // 8B LDS store

#define MFMA16(a,b,c) __builtin_amdgcn_mfma_f32_16x16x32_bf16(a,b,c,0,0,0)

__device__ __forceinline__ float bf2f(unsigned short u) {
    return __uint_as_float(((unsigned int)u) << 16);
}
__device__ __forceinline__ float bfl(unsigned int u) { return __uint_as_float(u << 16); }
__device__ __forceinline__ float bfh(unsigned int u) { return __uint_as_float(u & 0xffff0000u); }
__device__ __forceinline__ unsigned short f2bf(float f) {
    unsigned int u = __float_as_uint(f);
    return (unsigned short)((u + 0x7fffu + ((u >> 16) & 1u)) >> 16);
}

// dtype-agnostic scalar load: F32 -> float, else bf16 bits
template<bool F32>
__device__ __forceinline__ float ld1(const void* p, size_t i) {
    if constexpr (F32) return ((const float*)p)[i];
    else               return bf2f(((const unsigned short*)p)[i]);
}

// 8 consecutive elements -> bf16x8 fragment (fp32: convert; bf16: direct 16B load)
template<bool F32>
__device__ __forceinline__ bf16x8 ldfrag8(const void* p, int idx) {
    bf16x8 r;
    if constexpr (F32) {
        const float* f = (const float*)p + idx;
        float4 a = *(const float4*)f;
        float4 b = *(const float4*)(f + 4);
        r[0] = (short)f2bf(a.x); r[1] = (short)f2bf(a.y);
        r[2] = (short)f2bf(a.z); r[3] = (short)f2bf(a.w);
        r[4] = (short)f2bf(b.x); r[5] = (short)f2bf(b.y);
        r[6] = (short)f2bf(b.z); r[7] = (short)f2bf(b.w);
    } else {
        r = *(const bf16x8*)((const unsigned short*)p + idx);
    }
    return r;
}

// Detect fp32 data read as ushorts: lo-half mantissa words hit exp==0xFF
// (NaN pattern) with p~1/256; bf16 N(0,1) data never has exp==0xFF.
__device__ __forceinline__ bool detect_f32(const unsigned short* x) {
    int cnt = 0;
    for (int i = threadIdx.x; i < 8192; i += 256) {
        unsigned short u = x[i];
        cnt += ((u & 0x7F80u) == 0x7F80u) ? 1 : 0;
    }
    #pragma unroll
    for (int d = 1; d < 64; d <<= 1) cnt += __shfl_xor(cnt, d, 64);
    __shared__ int dsh[4];
    int wid = threadIdx.x >> 6;
    if ((threadIdx.x & 63) == 0) dsh[wid] = cnt;
    __syncthreads();
    int total = dsh[0] + dsh[1] + dsh[2] + dsh[3];
    __syncthreads();
    return total >= 2;
}

// ---------------------------------------------------------------------------
// Kernel 1 (unchanged this round): fused value/key 1x1 convs + BN + channel
// softmax + context matmul via MFMA. Grid: NB*S_CHUNKS=512 blocks, 256 threads.
// ---------------------------------------------------------------------------
template<bool F32>
__device__ void ctx_impl(const void* __restrict__ xv, const void* __restrict__ Wv,
                         const void* __restrict__ bv, const void* __restrict__ Wm,
                         const void* __restrict__ bm, const void* __restrict__ g_,
                         const void* __restrict__ be_, const void* __restrict__ me_,
                         const void* __restrict__ va_, float* __restrict__ ctx,
                         char* XTb, char* KTb, char* VTb)
{
    const int tid  = threadIdx.x;
    const int b    = blockIdx.x / S_CHUNKS;
    const int s    = blockIdx.x % S_CHUNKS;
    const int lane = tid & 63;
    const int wid  = tid >> 6;
    const int lh   = lane >> 4;   // 0..3
    const int ll   = lane & 15;   // 0..15

    // ---- per-lane BN/bias params for the 16 conv-D o-values: o = 16*(q>>2) + 4*lh + (q&3)
    float scale16[16], off16[16], bv16[16];
    #pragma unroll
    for (int q = 0; q < 16; ++q) {
        int o = 16 * (q >> 2) + 4 * lh + (q & 3);
        float sc = ld1<F32>(g_, o) * (1.0f / sqrtf(ld1<F32>(va_, o) + BN_EPS));
        scale16[q] = sc;
        off16[q]   = (ld1<F32>(bm, o) - ld1<F32>(me_, o)) * sc + ld1<F32>(be_, o);
        bv16[q]    = ld1<F32>(bv, o);
    }

    // ---- W fragments in registers (A-operand): row o = 16*ot + ll, k = 32*kk + 8*lh
    bf16x8 wvf[4][2], wmf[4][2];   // 64 VGPRs
    #pragma unroll
    for (int ot = 0; ot < 4; ++ot)
        #pragma unroll
        for (int kk = 0; kk < 2; ++kk) {
            int idx = (16 * ot + ll) * 64 + 32 * kk + 8 * lh;
            wvf[ot][kk] = ldfrag8<F32>(Wv, idx);
            wmf[ot][kk] = ldfrag8<F32>(Wm, idx);
        }

    // ---- ctx accumulators: wave owns i-tile = wid, j-tiles 0..3
    f32x4 cacc[4];
    #pragma unroll
    for (int tj = 0; tj < 4; ++tj)
        #pragma unroll
        for (int e = 0; e < 4; ++e) cacc[tj][e] = 0.0f;

    const int c0 = 16 * wid + 4 * lh;   // staging: 4 consecutive channels
    const int p0 = ll * 4;              // staging: 4 consecutive positions
    const int pB = 16 * wid + ll;       // this lane's output column p
    const size_t xbase = (size_t)b * (NC * NHW);

    for (int t = s; t < NTILES; t += S_CHUNKS) {
        // ---- A: stage XT[p][c] bf16, swizzled. Coalesced global reads (16 lanes
        // x consecutive p), transposed b64 LDS writes (4 bf16 along c).
        {
            unsigned short vs[4][4];   // [ci][pi]
            if constexpr (F32) {
                const float* xp = (const float*)xv + xbase + (size_t)t * 64 + p0;
                #pragma unroll
                for (int ci = 0; ci < 4; ++ci) {
                    float4 v = *(const float4*)(xp + (size_t)(c0 + ci) * NHW);
                    vs[ci][0] = f2bf(v.x); vs[ci][1] = f2bf(v.y);
                    vs[ci][2] = f2bf(v.z); vs[ci][3] = f2bf(v.w);
                }
            } else {
                const unsigned short* xp = (const unsigned short*)xv + xbase + (size_t)t * 64 + p0;
                #pragma unroll
                for (int ci = 0; ci < 4; ++ci) {
                    uint2 v = *(const uint2*)(xp + (size_t)(c0 + ci) * NHW);
                    vs[ci][0] = (unsigned short)(v.x & 0xffffu);
                    vs[ci][1] = (unsigned short)(v.x >> 16);
                    vs[ci][2] = (unsigned short)(v.y & 0xffffu);
                    vs[ci][3] = (unsigned short)(v.y >> 16);
                }
            }
            #pragma unroll
            for (int pi = 0; pi < 4; ++pi) {
                int p = p0 + pi;
                int off = ((p << 7) + (c0 << 1)) ^ ((p & 7) << 4);
                us4 w; w[0] = vs[0][pi]; w[1] = vs[1][pi]; w[2] = vs[2][pi]; w[3] = vs[3][pi];
                *(us4*)(XTb + off) = w;
            }
        }
        __syncthreads();   // XT visible; prev-iter KT/VT readers (mm2) done

        // ---- C: conv MFMAs. B-frag = XT row pB, shared by 4 o-tiles x 2 convs.
        f32x4 kacc[4], vacc[4];
        #pragma unroll
        for (int q = 0; q < 4; ++q)
            #pragma unroll
            for (int e = 0; e < 4; ++e) { kacc[q][e] = 0.0f; vacc[q][e] = 0.0f; }

        #pragma unroll
        for (int kk = 0; kk < 2; ++kk) {
            int off = ((pB << 7) + ((32 * kk + 8 * lh) << 1)) ^ ((pB & 7) << 4);
            bf16x8 xb = *(const bf16x8*)(XTb + off);
            #pragma unroll
            for (int ot = 0; ot < 4; ++ot) {
                vacc[ot] = MFMA16(wvf[ot][kk], xb, vacc[ot]);
                kacc[ot] = MFMA16(wmf[ot][kk], xb, kacc[ot]);
            }
        }

        // ---- softmax over o at column pB: 16 in-lane values + butterfly over lh
        float kb[16];
        float mx = -1e30f;
        #pragma unroll
        for (int q = 0; q < 16; ++q) {
            float v = fmaf(kacc[q >> 2][q & 3], scale16[q], off16[q]);
            kb[q] = v;
            mx = fmaxf(mx, v);
        }
        mx = fmaxf(mx, __shfl_xor(mx, 16, 64));
        mx = fmaxf(mx, __shfl_xor(mx, 32, 64));
        float ss = 0.0f;
        #pragma unroll
        for (int q = 0; q < 16; ++q) {
            float e = __expf(kb[q] - mx);
            kb[q] = e;
            ss += e;
        }
        ss += __shfl_xor(ss, 16, 64);
        ss += __shfl_xor(ss, 32, 64);
        float rs = 1.0f / ss;

        // ---- D: write KT/VT[o][p] bf16 (swizzled). lanes 0-15 write 32B runs -> conflict-free
        #pragma unroll
        for (int q = 0; q < 16; ++q) {
            int o = 16 * (q >> 2) + 4 * lh + (q & 3);
            int off = ((o << 7) + (pB << 1)) ^ ((o & 7) << 4);
            *(unsigned short*)(KTb + off) = f2bf(kb[q] * rs);
            *(unsigned short*)(VTb + off) = f2bf(vacc[q >> 2][q & 3] + bv16[q]);
        }
        __syncthreads();   // KT/VT complete; XT consumed

        // ---- E: ctx MFMAs: D[i][j] += sum_p K[i][p]*V[j][p] (k = p, 2 steps)
        #pragma unroll
        for (int kk = 0; kk < 2; ++kk) {
            int ra = 16 * wid + ll;
            int aoff = ((ra << 7) + ((32 * kk + 8 * lh) << 1)) ^ ((ra & 7) << 4);
            bf16x8 af = *(const bf16x8*)(KTb + aoff);
            #pragma unroll
            for (int tj = 0; tj < 4; ++tj) {
                int rb = 16 * tj + ll;
                int boff = ((rb << 7) + ((32 * kk + 8 * lh) << 1)) ^ ((rb & 7) << 4);
                bf16x8 bfr = *(const bf16x8*)(VTb + boff);
                cacc[tj] = MFMA16(af, bfr, cacc[tj]);
            }
        }
    }

    // ---- epilogue: ctx[i][j], i = 16*wid + 4*lh + r (C/D row map), j = 16*tj + ll
    float* cb = ctx + ((size_t)b << 12);
    #pragma unroll
    for (int tj = 0; tj < 4; ++tj)
        #pragma unroll
        for (int r = 0; r < 4; ++r)
            atomicAdd(&cb[(16 * wid + 4 * lh + r) * 64 + 16 * tj + ll], cacc[tj][r]);
}

__global__ __launch_bounds__(256) void ctx_kernel(
    const void* __restrict__ x, const void* __restrict__ Wv, const void* __restrict__ bv,
    const void* __restrict__ Wm, const void* __restrict__ bm, const void* __restrict__ g_,
    const void* __restrict__ be_, const void* __restrict__ me_, const void* __restrict__ va_,
    float* __restrict__ ctx)
{
    __shared__ __align__(16) char XTb[8192];   // XT[p][c] bf16, swizzled
    __shared__ __align__(16) char KTb[8192];   // Ksm[o][p] bf16, swizzled
    __shared__ __align__(16) char VTb[8192];   // V[o][p] bf16, swizzled
    if (detect_f32((const unsigned short*)x))
        ctx_impl<true >(x, Wv, bv, Wm, bm, g_, be_, me_, va_, ctx, XTb, KTb, VTb);
    else
        ctx_impl<false>(x, Wv, bv, Wm, bm, g_, be_, me_, va_, ctx, XTb, KTb, VTb);
}

// ---------------------------------------------------------------------------
// Kernel 2 (vectorized rewrite): per-(b,c) plane — recompute 9 dynamic weights
// from ctx (sigmoid + grouped fc) then depthwise 3x3 conv, pad 1.
// Each thread computes a 1x4 pixel quad: per quad 3 rows x (aligned 16B mid
// vector + 2 predicated edge scalars) = 9 loads + 1 vector store, replacing
// 36 scalar loads + 4 scalar stores. Grid: NB*NC=4096 blocks.
// ---------------------------------------------------------------------------
#define NQX (NW/4)           // 28 quads per row
#define NQUADS (NH*NQX)      // 3136 quads per plane

template<bool F32>
__device__ void dwconv_impl(const void* __restrict__ xv, const float* __restrict__ ctx,
                            const void* __restrict__ Wfc, const void* __restrict__ bfc,
                            void* __restrict__ outv, float* wsm, float* attS)
{
    const int bc = blockIdx.x;
    const int b = bc >> 6, i = bc & 63;
    const int tid = threadIdx.x, lane = tid & 63, wid = tid >> 6;

    if (wid == 0) {
        float cv = ctx[((size_t)b << 12) + (i << 6) + lane];
        attS[lane] = 1.0f / (1.0f + __expf(-cv));
    }
    __syncthreads();

    for (int j = wid; j < 9; j += 4) {
        float p = attS[lane] * ld1<F32>(Wfc, (size_t)(i * 9 + j) * 64 + lane);
        #pragma unroll
        for (int d = 1; d < 64; d <<= 1) p += __shfl_xor(p, d, 64);
        if (lane == 0) wsm[j] = p + ld1<F32>(bfc, i * 9 + j);
    }
    __syncthreads();

    const float w9[9] = { wsm[0], wsm[1], wsm[2], wsm[3], wsm[4],
                          wsm[5], wsm[6], wsm[7], wsm[8] };
    const size_t base = (size_t)bc * NHW;

    for (int q = tid; q < NQUADS; q += 256) {
        int y  = q / NQX;
        int qx = q - y * NQX;
        int x0 = qx << 2;
        float a0 = 0.0f, a1 = 0.0f, a2 = 0.0f, a3 = 0.0f;

        #pragma unroll
        for (int kr = 0; kr < 3; ++kr) {
            int r = y + kr - 1;
            if (r >= 0 && r < NH) {
                size_t rb = base + (size_t)r * NW + x0;
                float m0, m1, m2, m3;
                if constexpr (F32) {
                    float4 m = *(const float4*)((const float*)xv + rb);
                    m0 = m.x; m1 = m.y; m2 = m.z; m3 = m.w;
                } else {
                    uint2 v = *(const uint2*)((const unsigned short*)xv + rb);
                    m0 = bfl(v.x); m1 = bfh(v.x); m2 = bfl(v.y); m3 = bfh(v.y);
                }
                float le = (x0 > 0)      ? ld1<F32>(xv, rb - 1) : 0.0f;
                float ri = (x0 + 4 < NW) ? ld1<F32>(xv, rb + 4) : 0.0f;
                const float wl = w9[kr * 3], wm = w9[kr * 3 + 1], wr = w9[kr * 3 + 2];
                a0 = fmaf(wl, le, fmaf(wm, m0, fmaf(wr, m1, a0)));
                a1 = fmaf(wl, m0, fmaf(wm, m1, fmaf(wr, m2, a1)));
                a2 = fmaf(wl, m1, fmaf(wm, m2, fmaf(wr, m3, a2)));
                a3 = fmaf(wl, m2, fmaf(wm, m3, fmaf(wr, ri, a3)));
            }
        }

        size_t ob = base + (size_t)y * NW + x0;
        if constexpr (F32) {
            float4 o; o.x = a0; o.y = a1; o.z = a2; o.w = a3;
            *(float4*)((float*)outv + ob) = o;
        } else {
            us4 o; o[0] = f2bf(a0); o[1] = f2bf(a1); o[2] = f2bf(a2); o[3] = f2bf(a3);
            *(us4*)((unsigned short*)outv + ob) = o;
        }
    }
}

__global__ __launch_bounds__(256) void dwconv_kernel(
    const void* __restrict__ x, const float* __restrict__ ctx,
    const void* __restrict__ Wfc, const void* __restrict__ bfc, void* __restrict__ out)
{
    __shared__ float wsm[12];
    __shared__ float attS[64];
    if (detect_f32((const unsigned short*)x))
        dwconv_impl<true >(x, ctx, Wfc, bfc, out, wsm, attS);
    else
        dwconv_impl<false>(x, ctx, Wfc, bfc, out, wsm, attS);
}

extern "C" void kernel_launch(void* const* d_in, const int* in_sizes, int n_in,
                              void* d_out, int out_size, void* d_ws, size_t ws_size,
                              hipStream_t stream) {
    const void* x     = d_in[0];
    const void* Wv    = d_in[1];
    const void* bv    = d_in[2];
    const void* Wm    = d_in[3];
    const void* bm    = d_in[4];
    const void* gamma = d_in[5];
    const void* beta  = d_in[6];
    const void* mean  = d_in[7];
    const void* var   = d_in[8];
    const void* Wfc   = d_in[9];
    const void* bfc   = d_in[10];

    float* ctx = (float*)d_ws;   // exactly 64*64*64*4 = 1,048,576 bytes — total ws use

    hipMemsetAsync(ctx, 0, (size_t)NB * NC * NC * sizeof(float), stream);
    ctx_kernel<<<NB * S_CHUNKS, 256, 0, stream>>>(x, Wv, bv, Wm, bm, gamma, beta, mean, var, ctx);
    dwconv_kernel<<<NB * NC, 256, 0, stream>>>(x, ctx, Wfc, bfc, d_out);
}